// Round 1
// baseline (908.753 us; speedup 1.0000x reference)
//
#include <hip/hip_runtime.h>
#include <math.h>

#define NB 4
#define NH 16
#define SL 1024
#define DH 64
#define TQ 32
#define KT 64
#define NT 256
#define NEGV -1e9f
#define SCALE 0.125f

// Scores/P LDS layout: transposed [k][q], 32 floats per row, XOR-swizzled:
//   addr(k,q) = k*32 + (q ^ ((k&7)<<2))
// - score writes (lane = k, fixed q): <=4-way bank conflict
// - PV p-reads (k uniform across wave): conflict-free aligned b128
__global__ __launch_bounds__(NT, 1) void attn_fp32(
    const float* __restrict__ Q, const float* __restrict__ K,
    const float* __restrict__ V, const int* __restrict__ M,
    float* __restrict__ O, float* __restrict__ P)
{
    __shared__ float sST[SL * TQ];      // 131072 B  scores -> p (transposed)
    __shared__ float sT[KT][DH + 4];    // 17408 B   K tile, then V tile (row pad 68 floats: 16B-aligned rows)

    const int t = threadIdx.x;
    const int l = t & 63;
    const int w = __builtin_amdgcn_readfirstlane(t >> 6);   // wave id 0..3 (wave-uniform)
    const int qt = blockIdx.x, h = blockIdx.y, b = blockIdx.z;
    const int q0 = qt * TQ;

    const size_t hoff = ((size_t)(b * NH + h)) * SL * DH;
    const float* Qh = Q + hoff + (size_t)q0 * DH;
    const float* Kh = K + hoff;
    const float* Vh = V + hoff;
    const int*   Mh = M + ((size_t)b * SL + q0) * SL;          // mask [B,1,L,L]
    float*       Ph = P + (((size_t)(b * NH + h)) * SL + q0) * SL;
    float*       Oh = O + hoff + (size_t)q0 * DH;

    // ================= Phase A: scores =================
    for (int kt = 0; kt < SL / KT; ++kt) {
        const int k0 = kt * KT;
        __syncthreads();                       // protect sT from previous tile's readers
        {   // stage K tile: 64 rows x 64 d, coalesced float4
            const float4* src = (const float4*)(Kh + (size_t)k0 * DH);
            #pragma unroll
            for (int r = 0; r < 4; ++r) {
                int i = r * NT + t;            // 0..1023 float4s
                float4 v = src[i];
                *(float4*)&sT[i >> 4][(i & 15) << 2] = v;
            }
        }
        __syncthreads();

        // wave w computes rows q = w*8..w*8+7, lane l = k-within-tile
        float acc[8];
        #pragma unroll
        for (int i = 0; i < 8; ++i) acc[i] = 0.f;

        for (int d4 = 0; d4 < DH; d4 += 4) {
            float4 kv = *(const float4*)&sT[l][d4];     // per-lane b128, conflict-free-equivalent
            #pragma unroll
            for (int i = 0; i < 8; ++i) {
                const int q = w * 8 + i;
                // wave-uniform address -> scalar load (SGPR operand for the FMAs)
                float4 qv = *(const float4*)(Qh + q * DH + d4);
                acc[i] = fmaf(qv.x, kv.x, acc[i]);
                acc[i] = fmaf(qv.y, kv.y, acc[i]);
                acc[i] = fmaf(qv.z, kv.z, acc[i]);
                acc[i] = fmaf(qv.w, kv.w, acc[i]);
            }
        }

        const int kg = k0 + l;
        const int sw = (kg & 7) << 2;
        #pragma unroll
        for (int i = 0; i < 8; ++i) {
            const int q = w * 8 + i;
            const int mval = Mh[(size_t)q * SL + kg];   // coalesced across lanes
            const float s = (mval == 0) ? NEGV : acc[i] * SCALE;
            sST[kg * TQ + (q ^ sw)] = s;
        }
    }
    __syncthreads();

    // ================= Phase B: softmax stats (registers, per wave) =================
    float mrow[8], inv[8];
    #pragma unroll
    for (int i = 0; i < 8; ++i) {
        const int q = w * 8 + i;
        float m = -INFINITY;
        for (int kt = 0; kt < 16; ++kt) {
            const int k = kt * 64 + l;
            const float s = sST[k * TQ + (q ^ ((k & 7) << 2))];
            m = fmaxf(m, s);
        }
        #pragma unroll
        for (int off = 32; off; off >>= 1) m = fmaxf(m, __shfl_xor(m, off));
        float sum = 0.f;
        for (int kt = 0; kt < 16; ++kt) {
            const int k = kt * 64 + l;
            const float s = sST[k * TQ + (q ^ ((k & 7) << 2))];
            sum += __expf(s - m);               // masked entries: exp(-1e9 - m) == 0
        }
        #pragma unroll
        for (int off = 32; off; off >>= 1) sum += __shfl_xor(sum, off);
        mrow[i] = m;
        inv[i] = 1.f / sum;
    }

    // ================= Phase C: p materialization + PV =================
    float outp[8][4];
    #pragma unroll
    for (int i = 0; i < 8; ++i)
        #pragma unroll
        for (int j = 0; j < 4; ++j) outp[i][j] = 0.f;

    const int qg = l >> 4;       // 0..3 : q rows qg*8..qg*8+7
    const int dg = l & 15;       // d = dg*4..dg*4+3

    for (int kt = 0; kt < 16; ++kt) {
        const int k0 = kt * KT;
        __syncthreads();                       // prior PV done with sT
        {   // stage V tile
            const float4* src = (const float4*)(Vh + (size_t)k0 * DH);
            #pragma unroll
            for (int r = 0; r < 4; ++r) {
                int i = r * NT + t;
                float4 v = src[i];
                *(float4*)&sT[i >> 4][(i & 15) << 2] = v;
            }
        }
        // p for own rows, lane = k
        {
            const int kg = k0 + l;
            const int sw = (kg & 7) << 2;
            #pragma unroll
            for (int i = 0; i < 8; ++i) {
                const int q = w * 8 + i;
                const int idx = kg * TQ + (q ^ sw);
                const float s = sST[idx];
                // forces exact 0 on masked entries (also fixes fully-masked rows)
                const float p = (s < -1e8f) ? 0.f : __expf(s - mrow[i]) * inv[i];
                Ph[(size_t)q * SL + kg] = p;    // coalesced global write
                sST[idx] = p;                   // overwrite score with p
            }
        }
        __syncthreads();

        // PV: wave w handles k = k0 + w*16 .. +15 ; lane owns 8q x 4d register tile
        #pragma unroll
        for (int kk = 0; kk < 16; ++kk) {
            const int k = k0 + w * 16 + kk;     // wave-uniform
            const int swz = (k & 7) << 2;
            const float4 va = *(const float4*)&sT[k - k0][dg << 2];
            const int qb0 = (qg * 8 + 0) ^ swz;
            const int qb1 = (qg * 8 + 4) ^ swz;
            const float4 p0 = *(const float4*)&sST[k * TQ + qb0];
            const float4 p1 = *(const float4*)&sST[k * TQ + qb1];
            const float pr[8] = {p0.x, p0.y, p0.z, p0.w, p1.x, p1.y, p1.z, p1.w};
            #pragma unroll
            for (int i = 0; i < 8; ++i) {
                outp[i][0] = fmaf(pr[i], va.x, outp[i][0]);
                outp[i][1] = fmaf(pr[i], va.y, outp[i][1]);
                outp[i][2] = fmaf(pr[i], va.z, outp[i][2]);
                outp[i][3] = fmaf(pr[i], va.w, outp[i][3]);
            }
        }
    }

    // ================= Cross-wave out reduction =================
    // Partials land in rows k=0..255 of sST; all PV reads of those rows finished long ago,
    // and the loop-top barriers keep waves within one tile of each other.
    __syncthreads();
    #pragma unroll
    for (int i = 0; i < 8; ++i) {
        const int q = qg * 8 + i;
        float4 vv = make_float4(outp[i][0], outp[i][1], outp[i][2], outp[i][3]);
        *(float4*)&sST[w * (TQ * DH) + q * DH + (dg << 2)] = vv;
    }
    __syncthreads();
    #pragma unroll
    for (int r = 0; r < 2; ++r) {
        const int f4 = r * NT + t;             // 0..511 float4s of the 32x64 out tile
        const float4 a = *(const float4*)&sST[0 * (TQ * DH) + f4 * 4];
        const float4 bb = *(const float4*)&sST[1 * (TQ * DH) + f4 * 4];
        const float4 c = *(const float4*)&sST[2 * (TQ * DH) + f4 * 4];
        const float4 d = *(const float4*)&sST[3 * (TQ * DH) + f4 * 4];
        float4 s;
        s.x = a.x + bb.x + c.x + d.x;
        s.y = a.y + bb.y + c.y + d.y;
        s.z = a.z + bb.z + c.z + d.z;
        s.w = a.w + bb.w + c.w + d.w;
        *(float4*)(Oh + (size_t)f4 * 4) = s;
    }
}

extern "C" void kernel_launch(void* const* d_in, const int* in_sizes, int n_in,
                              void* d_out, int out_size, void* d_ws, size_t ws_size,
                              hipStream_t stream) {
    const float* Q = (const float*)d_in[0];
    const float* K = (const float*)d_in[1];
    const float* V = (const float*)d_in[2];
    const int*   M = (const int*)d_in[3];
    float* O = (float*)d_out;
    float* P = O + (size_t)NB * NH * SL * DH;   // outputs concatenated: out, p_attn

    dim3 grid(SL / TQ, NH, NB);
    dim3 block(NT, 1, 1);
    hipLaunchKernelGGL(attn_fp32, grid, block, 0, stream, Q, K, V, M, O, P);
}

// Round 2
// 199.148 us; speedup vs baseline: 4.5632x; 4.5632x over previous
//
#include <hip/hip_runtime.h>
#include <math.h>

typedef __attribute__((ext_vector_type(8))) short short8;
typedef __attribute__((ext_vector_type(4))) float f32x4;

#define NB 4
#define NH 16
#define SL 1024
#define DH 64
#define BQ 64      // q rows per block (4 waves x 16)
#define WQ 16      // q rows per wave
#define KTL 64     // k rows per tile
#define NT 256
#define NKT (SL / KTL)

__device__ __forceinline__ unsigned short bf_rne(float x) {
    unsigned int u = __float_as_uint(x);
    u += 0x7fffu + ((u >> 16) & 1u);
    return (unsigned short)(u >> 16);
}
// x ~= hi + lo with |err| <= 2^-17 |x|
__device__ __forceinline__ void bf_split(float x, unsigned short& h, unsigned short& l) {
    unsigned int u = __float_as_uint(x);
    h = (unsigned short)(u >> 16);                       // truncate
    float r = x - __uint_as_float(u & 0xffff0000u);      // exact residual
    l = bf_rne(r);
}

#define MFMA(a, b, c) __builtin_amdgcn_mfma_f32_16x16x32_bf16(a, b, c, 0, 0, 0)

__global__ __launch_bounds__(NT, 2) void attn_mfma(
    const float* __restrict__ Q, const float* __restrict__ K,
    const float* __restrict__ V, const int* __restrict__ M,
    float* __restrict__ O, float* __restrict__ P)
{
    // All tiles XOR-swizzled on the minor index (16B granule): idx ^= ((row&7)<<3)
    __shared__ unsigned short sKhi[KTL][DH];   // [kseq][d]   8KB
    __shared__ unsigned short sKlo[KTL][DH];
    __shared__ unsigned short sVhi[DH][KTL];   // [d][kseq]   8KB
    __shared__ unsigned short sVlo[DH][KTL];
    __shared__ unsigned short sPhi[4][WQ][KTL];// per-wave [q][kseq] 8KB total
    __shared__ unsigned short sPlo[4][WQ][KTL];

    const int t = threadIdx.x;
    const int l = t & 63;
    const int w = t >> 6;
    const int lg = l >> 4;     // lane group 0..3
    const int lr = l & 15;     // row/col within fragment

    const int hh_ = blockIdx.y, b = blockIdx.z;
    const int qb = blockIdx.x * BQ + w * WQ;

    const size_t hoff = (size_t)(b * NH + hh_) * SL * DH;
    const float* Kh = K + hoff;
    const float* Vh = V + hoff;
    const int*   Mw = M + ((size_t)b * SL + qb) * SL;
    float*       Pw = P + ((size_t)(b * NH + hh_) * SL + qb) * SL;
    float*       Ow = O + hoff + (size_t)qb * DH;

    // ---- Q fragments (B operand of swapped QK: B[k=d][col=q]), scale folded in ----
    short8 qhi[2], qlo[2];
    {
        const float* src0 = Q + hoff + (size_t)(qb + lr) * DH + lg * 8;
        #pragma unroll
        for (int ds = 0; ds < 2; ++ds) {
            const float* src = src0 + ds * 32;
            float4 a = *(const float4*)src;
            float4 bb = *(const float4*)(src + 4);
            float vals[8] = {a.x, a.y, a.z, a.w, bb.x, bb.y, bb.z, bb.w};
            #pragma unroll
            for (int j = 0; j < 8; ++j) {
                unsigned short hv, lv;
                bf_split(vals[j] * 0.125f, hv, lv);
                qhi[ds][j] = (short)hv;
                qlo[ds][j] = (short)lv;
            }
        }
    }

    auto stageK = [&](int k0) {
        #pragma unroll
        for (int u = 0; u < 2; ++u) {
            int idx = u * NT + t;          // 0..511
            int kr = idx >> 3;             // kseq row
            int dc = (idx & 7) * 8;        // d chunk
            const float* src = Kh + (size_t)(k0 + kr) * DH + dc;
            float4 a = *(const float4*)src;
            float4 bb = *(const float4*)(src + 4);
            float vals[8] = {a.x, a.y, a.z, a.w, bb.x, bb.y, bb.z, bb.w};
            unsigned int ph[4], pl[4];
            #pragma unroll
            for (int j = 0; j < 4; ++j) {
                unsigned short h0, l0, h1, l1;
                bf_split(vals[2 * j], h0, l0);
                bf_split(vals[2 * j + 1], h1, l1);
                ph[j] = (unsigned int)h0 | ((unsigned int)h1 << 16);
                pl[j] = (unsigned int)l0 | ((unsigned int)l1 << 16);
            }
            int dsw = dc ^ ((kr & 7) << 3);
            uint4 uh = make_uint4(ph[0], ph[1], ph[2], ph[3]);
            uint4 ul = make_uint4(pl[0], pl[1], pl[2], pl[3]);
            *(uint4*)&sKhi[kr][dsw] = uh;
            *(uint4*)&sKlo[kr][dsw] = ul;
        }
    };

    // ================= Pass 1: softmax stats =================
    float m = -INFINITY, sum = 0.f;

    for (int kt = 0; kt < NKT; ++kt) {
        const int k0 = kt * KTL;
        __syncthreads();
        stageK(k0);
        __syncthreads();

        f32x4 acc[4];
        #pragma unroll
        for (int st = 0; st < 4; ++st) {
            const int krow = st * 16 + lr;
            const int sw = (krow & 7) << 3;
            f32x4 c = {0.f, 0.f, 0.f, 0.f};
            #pragma unroll
            for (int ds = 0; ds < 2; ++ds) {
                int dc = (ds * 32 + lg * 8) ^ sw;
                short8 ah = *(const short8*)&sKhi[krow][dc];
                short8 al = *(const short8*)&sKlo[krow][dc];
                c = MFMA(ah, qhi[ds], c);
                c = MFMA(ah, qlo[ds], c);
                c = MFMA(al, qhi[ds], c);
            }
            acc[st] = c;
        }

        float s[16];
        #pragma unroll
        for (int st = 0; st < 4; ++st) {
            const int4 mv = *(const int4*)(Mw + (size_t)lr * SL + k0 + st * 16 + lg * 4);
            s[st * 4 + 0] = mv.x ? acc[st][0] : -1e9f;
            s[st * 4 + 1] = mv.y ? acc[st][1] : -1e9f;
            s[st * 4 + 2] = mv.z ? acc[st][2] : -1e9f;
            s[st * 4 + 3] = mv.w ? acc[st][3] : -1e9f;
        }
        float tmax = s[0];
        #pragma unroll
        for (int j = 1; j < 16; ++j) tmax = fmaxf(tmax, s[j]);
        tmax = fmaxf(tmax, __shfl_xor(tmax, 16));
        tmax = fmaxf(tmax, __shfl_xor(tmax, 32));
        const float mn = fmaxf(m, tmax);
        float ts = 0.f;
        #pragma unroll
        for (int j = 0; j < 16; ++j) ts += __expf(s[j] - mn);
        ts += __shfl_xor(ts, 16);
        ts += __shfl_xor(ts, 32);
        sum = sum * __expf(m - mn) + ts;
        m = mn;
    }
    const float inv = 1.f / sum;

    // ================= Pass 2: P + PV =================
    f32x4 oacc[4];
    #pragma unroll
    for (int mt = 0; mt < 4; ++mt) oacc[mt] = (f32x4){0.f, 0.f, 0.f, 0.f};

    for (int kt = 0; kt < NKT; ++kt) {
        const int k0 = kt * KTL;
        __syncthreads();
        stageK(k0);
        {   // stage V transposed: [d][kseq], split bf16
            int d0 = (t & 15) * 4;
            int kl0 = (t >> 4) * 4;
            float4 r[4];
            #pragma unroll
            for (int i = 0; i < 4; ++i)
                r[i] = *(const float4*)(Vh + (size_t)(k0 + kl0 + i) * DH + d0);
            const float* rp = (const float*)r;
            #pragma unroll
            for (int j = 0; j < 4; ++j) {
                unsigned short hv[4], lv[4];
                #pragma unroll
                for (int i = 0; i < 4; ++i) bf_split(rp[i * 4 + j], hv[i], lv[i]);
                int d = d0 + j;
                int csw = kl0 ^ ((d & 7) << 3);
                uint2 uh, ul;
                uh.x = (unsigned int)hv[0] | ((unsigned int)hv[1] << 16);
                uh.y = (unsigned int)hv[2] | ((unsigned int)hv[3] << 16);
                ul.x = (unsigned int)lv[0] | ((unsigned int)lv[1] << 16);
                ul.y = (unsigned int)lv[2] | ((unsigned int)lv[3] << 16);
                *(uint2*)&sVhi[d][csw] = uh;
                *(uint2*)&sVlo[d][csw] = ul;
            }
        }
        __syncthreads();

        // recompute S^T, finalize p, write global P + LDS P
        #pragma unroll
        for (int st = 0; st < 4; ++st) {
            const int krow = st * 16 + lr;
            const int sw = (krow & 7) << 3;
            f32x4 c = {0.f, 0.f, 0.f, 0.f};
            #pragma unroll
            for (int ds = 0; ds < 2; ++ds) {
                int dc = (ds * 32 + lg * 8) ^ sw;
                short8 ah = *(const short8*)&sKhi[krow][dc];
                short8 al = *(const short8*)&sKlo[krow][dc];
                c = MFMA(ah, qhi[ds], c);
                c = MFMA(ah, qlo[ds], c);
                c = MFMA(al, qhi[ds], c);
            }
            const int4 mv = *(const int4*)(Mw + (size_t)lr * SL + k0 + st * 16 + lg * 4);
            float p0 = mv.x ? __expf(c[0] - m) * inv : 0.f;
            float p1 = mv.y ? __expf(c[1] - m) * inv : 0.f;
            float p2 = mv.z ? __expf(c[2] - m) * inv : 0.f;
            float p3 = mv.w ? __expf(c[3] - m) * inv : 0.f;
            *(float4*)(Pw + (size_t)lr * SL + (k0 + st * 16 + lg * 4)) =
                make_float4(p0, p1, p2, p3);
            unsigned short hv[4], lv[4];
            bf_split(p0, hv[0], lv[0]);
            bf_split(p1, hv[1], lv[1]);
            bf_split(p2, hv[2], lv[2]);
            bf_split(p3, hv[3], lv[3]);
            int col = (st * 16 + lg * 4) ^ ((lr & 7) << 3);
            uint2 uh, ul;
            uh.x = (unsigned int)hv[0] | ((unsigned int)hv[1] << 16);
            uh.y = (unsigned int)hv[2] | ((unsigned int)hv[3] << 16);
            ul.x = (unsigned int)lv[0] | ((unsigned int)lv[1] << 16);
            ul.y = (unsigned int)lv[2] | ((unsigned int)lv[3] << 16);
            *(uint2*)&sPhi[w][lr][col] = uh;
            *(uint2*)&sPlo[w][lr][col] = ul;
        }

        // PV: O^T += V^T * P^T   (A = V^T frag, B = P frag from own LDS tile)
        short8 pbh[2], pbl[2];
        #pragma unroll
        for (int ks = 0; ks < 2; ++ks) {
            int col = (ks * 32 + lg * 8) ^ ((lr & 7) << 3);
            pbh[ks] = *(const short8*)&sPhi[w][lr][col];
            pbl[ks] = *(const short8*)&sPlo[w][lr][col];
        }
        #pragma unroll
        for (int mt = 0; mt < 4; ++mt) {
            const int d = mt * 16 + lr;
            const int swd = (d & 7) << 3;
            #pragma unroll
            for (int ks = 0; ks < 2; ++ks) {
                int col = (ks * 32 + lg * 8) ^ swd;
                short8 vh = *(const short8*)&sVhi[d][col];
                short8 vl = *(const short8*)&sVlo[d][col];
                oacc[mt] = MFMA(vh, pbh[ks], oacc[mt]);
                oacc[mt] = MFMA(vh, pbl[ks], oacc[mt]);
                oacc[mt] = MFMA(vl, pbh[ks], oacc[mt]);
            }
        }
    }

    // O^T C-frags -> O[q][d]; regs are consecutive d at fixed q -> float4 stores
    #pragma unroll
    for (int mt = 0; mt < 4; ++mt) {
        float4 o = make_float4(oacc[mt][0], oacc[mt][1], oacc[mt][2], oacc[mt][3]);
        *(float4*)(Ow + (size_t)lr * DH + mt * 16 + lg * 4) = o;
    }
}

extern "C" void kernel_launch(void* const* d_in, const int* in_sizes, int n_in,
                              void* d_out, int out_size, void* d_ws, size_t ws_size,
                              hipStream_t stream) {
    const float* Q = (const float*)d_in[0];
    const float* K = (const float*)d_in[1];
    const float* V = (const float*)d_in[2];
    const int*   M = (const int*)d_in[3];
    float* O = (float*)d_out;
    float* P = O + (size_t)NB * NH * SL * DH;   // outputs: out, p_attn

    dim3 grid(SL / BQ, NH, NB);
    dim3 block(NT, 1, 1);
    hipLaunchKernelGGL(attn_mfma, grid, block, 0, stream, Q, K, V, M, O, P);
}

// Round 3
// 177.914 us; speedup vs baseline: 5.1078x; 1.1193x over previous
//
#include <hip/hip_runtime.h>
#include <math.h>

typedef __attribute__((ext_vector_type(8))) short short8;
typedef __attribute__((ext_vector_type(4))) float f32x4;

#define NB 4
#define NH 16
#define SL 1024
#define DH 64
#define BQ 64      // q rows per block (4 waves x 16)
#define WQ 16      // q rows per wave
#define KTL 64     // k rows per tile
#define NT 256
#define NKT (SL / KTL)

#define TILE_SH (KTL * DH)              // 4096 shorts = 8 KB per tile blob
#define HEAD_SH (SL * DH)               // 65536 shorts per head
#define BLOB_SH ((size_t)NB * NH * HEAD_SH)   // 8 MB per blob

__device__ __forceinline__ unsigned short bf_rne(float x) {
    unsigned int u = __float_as_uint(x);
    u += 0x7fffu + ((u >> 16) & 1u);
    return (unsigned short)(u >> 16);
}
__device__ __forceinline__ void bf_split(float x, unsigned short& h, unsigned short& l) {
    unsigned int u = __float_as_uint(x);
    h = (unsigned short)(u >> 16);                       // truncate
    float r = x - __uint_as_float(u & 0xffff0000u);      // exact residual
    l = bf_rne(r);
}

typedef const __attribute__((address_space(1))) unsigned int guint_t;
typedef __attribute__((address_space(3))) unsigned int luint_t;
__device__ __forceinline__ void gload_lds16(const void* g, void* l) {
    __builtin_amdgcn_global_load_lds((guint_t*)g, (luint_t*)l, 16, 0, 0);
}

#define MFMA(a, b, c) __builtin_amdgcn_mfma_f32_16x16x32_bf16(a, b, c, 0, 0, 0)

// ============================================================================
// Prep: split K -> (khi,klo) tile-linear swizzled [kr][dc ^ ((kr&7)<<3)]
//       split V^T -> (vhi,vlo) tile-linear swizzled [d][kl ^ ((d&7)<<3)]
// Blob layouts match the main kernel's LDS byte order exactly, so staging is
// pure 16B global_load_lds DMA.
// ============================================================================
__global__ __launch_bounds__(NT, 4) void prep_split(
    const float* __restrict__ K, const float* __restrict__ V,
    unsigned short* __restrict__ khi, unsigned short* __restrict__ klo,
    unsigned short* __restrict__ vhi, unsigned short* __restrict__ vlo)
{
    __shared__ float sV[KTL][DH + 4];

    const int t = threadIdx.x;
    const int kt = blockIdx.x, h = blockIdx.y, b = blockIdx.z;
    const size_t goff = (size_t)(b * NH + h) * SL * DH + (size_t)kt * KTL * DH;
    const size_t toff = (size_t)(b * NH + h) * HEAD_SH + (size_t)kt * TILE_SH;

    // ---- K: granule (kr, c8), coalesced read + coalesced (permuted-in-line) write
    #pragma unroll
    for (int u = 0; u < 2; ++u) {
        int idx = u * NT + t;                 // 0..511
        int kr = idx >> 3, c8 = idx & 7;
        const float* src = K + goff + kr * DH + c8 * 8;
        float4 a = *(const float4*)src;
        float4 bb = *(const float4*)(src + 4);
        float vals[8] = {a.x, a.y, a.z, a.w, bb.x, bb.y, bb.z, bb.w};
        unsigned int ph[4], pl[4];
        #pragma unroll
        for (int j = 0; j < 4; ++j) {
            unsigned short h0, l0, h1, l1;
            bf_split(vals[2 * j], h0, l0);
            bf_split(vals[2 * j + 1], h1, l1);
            ph[j] = (unsigned int)h0 | ((unsigned int)h1 << 16);
            pl[j] = (unsigned int)l0 | ((unsigned int)l1 << 16);
        }
        int dsw = (c8 * 8) ^ ((kr & 7) << 3);
        *(uint4*)&khi[toff + kr * DH + dsw] = make_uint4(ph[0], ph[1], ph[2], ph[3]);
        *(uint4*)&klo[toff + kr * DH + dsw] = make_uint4(pl[0], pl[1], pl[2], pl[3]);
    }

    // ---- V: stage fp32 tile, transpose via LDS
    #pragma unroll
    for (int u = 0; u < 4; ++u) {
        int i = u * NT + t;                   // float4 id 0..1023
        float4 v = *(const float4*)(V + goff + (size_t)i * 4);
        *(float4*)&sV[i >> 4][(i & 15) * 4] = v;
    }
    __syncthreads();
    #pragma unroll
    for (int u = 0; u < 2; ++u) {
        int idx = u * NT + t;                 // granule (d, k8); d=idx&63 -> conflict-light LDS reads
        int d = idx & 63, k8 = idx >> 6;      // k8: 0..3 (u=0), 4..7 (u=1)
        float vals[8];
        #pragma unroll
        for (int j = 0; j < 8; ++j) vals[j] = sV[k8 * 8 + j][d];
        unsigned int ph[4], pl[4];
        #pragma unroll
        for (int j = 0; j < 4; ++j) {
            unsigned short h0, l0, h1, l1;
            bf_split(vals[2 * j], h0, l0);
            bf_split(vals[2 * j + 1], h1, l1);
            ph[j] = (unsigned int)h0 | ((unsigned int)h1 << 16);
            pl[j] = (unsigned int)l0 | ((unsigned int)l1 << 16);
        }
        int ksw = (k8 * 8) ^ ((d & 7) << 3);
        *(uint4*)&vhi[toff + d * KTL + ksw] = make_uint4(ph[0], ph[1], ph[2], ph[3]);
        *(uint4*)&vlo[toff + d * KTL + ksw] = make_uint4(pl[0], pl[1], pl[2], pl[3]);
    }
}

// ============================================================================
// Main: two-pass softmax attention, MFMA split-bf16, DMA-staged tiles
// ============================================================================
__global__ __launch_bounds__(NT, 3) void attn_main(
    const float* __restrict__ Q, const int* __restrict__ M,
    const unsigned short* __restrict__ khi, const unsigned short* __restrict__ klo,
    const unsigned short* __restrict__ vhi, const unsigned short* __restrict__ vlo,
    float* __restrict__ O, float* __restrict__ P)
{
    __shared__ unsigned short sKhi[KTL][DH];
    __shared__ unsigned short sKlo[KTL][DH];
    __shared__ unsigned short sVhi[DH][KTL];
    __shared__ unsigned short sVlo[DH][KTL];
    __shared__ unsigned short sPhi[4][WQ][KTL];
    __shared__ unsigned short sPlo[4][WQ][KTL];

    const int t = threadIdx.x;
    const int l = t & 63;
    const int w = __builtin_amdgcn_readfirstlane(t >> 6);
    const int lg = l >> 4, lr = l & 15;

    // XCD-aware swizzle: 1024 blocks -> XCD x owns contiguous newid chunk
    const int flat = blockIdx.x + (blockIdx.y << 4) + (blockIdx.z << 8);
    const int nid = (flat & 7) * 128 + (flat >> 3);
    const int qt = nid & 15;
    const int hh_ = (nid >> 4) & 15;
    const int b = nid >> 8;
    const int qb = qt * BQ + w * WQ;

    const size_t hoff = (size_t)(b * NH + hh_) * SL * DH;
    const size_t headsh = (size_t)(b * NH + hh_) * HEAD_SH;
    const int*   Mw = M + ((size_t)b * SL + qb) * SL;
    float*       Pw = P + ((size_t)(b * NH + hh_) * SL + qb) * SL;
    float*       Ow = O + hoff + (size_t)qb * DH;

    // ---- Q fragments (B operand of swapped QK), scale folded in ----
    short8 qhi[2], qlo[2];
    {
        const float* src0 = Q + hoff + (size_t)(qb + lr) * DH + lg * 8;
        #pragma unroll
        for (int ds = 0; ds < 2; ++ds) {
            const float* src = src0 + ds * 32;
            float4 a = *(const float4*)src;
            float4 bb = *(const float4*)(src + 4);
            float vals[8] = {a.x, a.y, a.z, a.w, bb.x, bb.y, bb.z, bb.w};
            #pragma unroll
            for (int j = 0; j < 8; ++j) {
                unsigned short hv, lv;
                bf_split(vals[j] * 0.125f, hv, lv);
                qhi[ds][j] = (short)hv;
                qlo[ds][j] = (short)lv;
            }
        }
    }

    auto stageK = [&](int kt) {
        const char* gh = (const char*)(khi + headsh + (size_t)kt * TILE_SH);
        const char* gl = (const char*)(klo + headsh + (size_t)kt * TILE_SH);
        #pragma unroll
        for (int u = 0; u < 2; ++u) {
            const int c = w * 2 + u;
            gload_lds16(gh + c * 1024 + l * 16, (char*)&sKhi[0][0] + c * 1024);
            gload_lds16(gl + c * 1024 + l * 16, (char*)&sKlo[0][0] + c * 1024);
        }
    };
    auto stageV = [&](int kt) {
        const char* gh = (const char*)(vhi + headsh + (size_t)kt * TILE_SH);
        const char* gl = (const char*)(vlo + headsh + (size_t)kt * TILE_SH);
        #pragma unroll
        for (int u = 0; u < 2; ++u) {
            const int c = w * 2 + u;
            gload_lds16(gh + c * 1024 + l * 16, (char*)&sVhi[0][0] + c * 1024);
            gload_lds16(gl + c * 1024 + l * 16, (char*)&sVlo[0][0] + c * 1024);
        }
    };

    // ================= Pass 1: softmax stats =================
    float m = -INFINITY, sum = 0.f;

    for (int kt = 0; kt < NKT; ++kt) {
        const int k0 = kt * KTL;
        __syncthreads();
        stageK(kt);
        __syncthreads();

        f32x4 acc[4];
        #pragma unroll
        for (int st = 0; st < 4; ++st) {
            const int krow = st * 16 + lr;
            const int sw = (krow & 7) << 3;
            f32x4 c = {0.f, 0.f, 0.f, 0.f};
            #pragma unroll
            for (int ds = 0; ds < 2; ++ds) {
                int dc = (ds * 32 + lg * 8) ^ sw;
                short8 ah = *(const short8*)&sKhi[krow][dc];
                short8 al = *(const short8*)&sKlo[krow][dc];
                c = MFMA(ah, qhi[ds], c);
                c = MFMA(ah, qlo[ds], c);
                c = MFMA(al, qhi[ds], c);
            }
            acc[st] = c;
        }

        float s[16];
        #pragma unroll
        for (int st = 0; st < 4; ++st) {
            const int4 mv = *(const int4*)(Mw + (size_t)lr * SL + k0 + st * 16 + lg * 4);
            s[st * 4 + 0] = mv.x ? acc[st][0] : -1e9f;
            s[st * 4 + 1] = mv.y ? acc[st][1] : -1e9f;
            s[st * 4 + 2] = mv.z ? acc[st][2] : -1e9f;
            s[st * 4 + 3] = mv.w ? acc[st][3] : -1e9f;
        }
        float tmax = s[0];
        #pragma unroll
        for (int j = 1; j < 16; ++j) tmax = fmaxf(tmax, s[j]);
        tmax = fmaxf(tmax, __shfl_xor(tmax, 16));
        tmax = fmaxf(tmax, __shfl_xor(tmax, 32));
        const float mn = fmaxf(m, tmax);
        float ts = 0.f;
        #pragma unroll
        for (int j = 0; j < 16; ++j) ts += __expf(s[j] - mn);
        ts += __shfl_xor(ts, 16);
        ts += __shfl_xor(ts, 32);
        sum = sum * __expf(m - mn) + ts;
        m = mn;
    }
    const float inv = 1.f / sum;

    // ================= Pass 2: P + PV =================
    f32x4 oacc[4];
    #pragma unroll
    for (int mt = 0; mt < 4; ++mt) oacc[mt] = (f32x4){0.f, 0.f, 0.f, 0.f};

    for (int kt = 0; kt < NKT; ++kt) {
        const int k0 = kt * KTL;
        __syncthreads();
        stageK(kt);
        stageV(kt);
        __syncthreads();

        #pragma unroll
        for (int st = 0; st < 4; ++st) {
            const int krow = st * 16 + lr;
            const int sw = (krow & 7) << 3;
            f32x4 c = {0.f, 0.f, 0.f, 0.f};
            #pragma unroll
            for (int ds = 0; ds < 2; ++ds) {
                int dc = (ds * 32 + lg * 8) ^ sw;
                short8 ah = *(const short8*)&sKhi[krow][dc];
                short8 al = *(const short8*)&sKlo[krow][dc];
                c = MFMA(ah, qhi[ds], c);
                c = MFMA(ah, qlo[ds], c);
                c = MFMA(al, qhi[ds], c);
            }
            const int4 mv = *(const int4*)(Mw + (size_t)lr * SL + k0 + st * 16 + lg * 4);
            float p0 = mv.x ? __expf(c[0] - m) * inv : 0.f;
            float p1 = mv.y ? __expf(c[1] - m) * inv : 0.f;
            float p2 = mv.z ? __expf(c[2] - m) * inv : 0.f;
            float p3 = mv.w ? __expf(c[3] - m) * inv : 0.f;
            *(float4*)(Pw + (size_t)lr * SL + (k0 + st * 16 + lg * 4)) =
                make_float4(p0, p1, p2, p3);
            unsigned short hv[4], lv[4];
            bf_split(p0, hv[0], lv[0]);
            bf_split(p1, hv[1], lv[1]);
            bf_split(p2, hv[2], lv[2]);
            bf_split(p3, hv[3], lv[3]);
            int col = (st * 16 + lg * 4) ^ ((lr & 7) << 3);
            uint2 uh, ul;
            uh.x = (unsigned int)hv[0] | ((unsigned int)hv[1] << 16);
            uh.y = (unsigned int)hv[2] | ((unsigned int)hv[3] << 16);
            ul.x = (unsigned int)lv[0] | ((unsigned int)lv[1] << 16);
            ul.y = (unsigned int)lv[2] | ((unsigned int)lv[3] << 16);
            *(uint2*)&sPhi[w][lr][col] = uh;
            *(uint2*)&sPlo[w][lr][col] = ul;
        }

        // PV: O^T += V^T * P^T
        short8 pbh[2], pbl[2];
        #pragma unroll
        for (int ks = 0; ks < 2; ++ks) {
            int col = (ks * 32 + lg * 8) ^ ((lr & 7) << 3);
            pbh[ks] = *(const short8*)&sPhi[w][lr][col];
            pbl[ks] = *(const short8*)&sPlo[w][lr][col];
        }
        #pragma unroll
        for (int mt = 0; mt < 4; ++mt) {
            const int d = mt * 16 + lr;
            const int swd = (d & 7) << 3;
            #pragma unroll
            for (int ks = 0; ks < 2; ++ks) {
                int col = (ks * 32 + lg * 8) ^ swd;
                short8 vh = *(const short8*)&sVhi[d][col];
                short8 vl = *(const short8*)&sVlo[d][col];
                oacc[mt] = MFMA(vh, pbh[ks], oacc[mt]);
                oacc[mt] = MFMA(vh, pbl[ks], oacc[mt]);
                oacc[mt] = MFMA(vl, pbh[ks], oacc[mt]);
            }
        }
    }

    #pragma unroll
    for (int mt = 0; mt < 4; ++mt) {
        float4 o = make_float4(oacc[mt][0], oacc[mt][1], oacc[mt][2], oacc[mt][3]);
        *(float4*)(Ow + (size_t)lr * DH + mt * 16 + lg * 4) = o;
    }
}

// ============================================================================
// Fallback (round-2 kernel) if workspace is too small for the blobs
// ============================================================================
__global__ __launch_bounds__(NT, 2) void attn_fallback(
    const float* __restrict__ Q, const float* __restrict__ K,
    const float* __restrict__ V, const int* __restrict__ M,
    float* __restrict__ O, float* __restrict__ P)
{
    __shared__ unsigned short sKhi[KTL][DH];
    __shared__ unsigned short sKlo[KTL][DH];
    __shared__ unsigned short sVhi[DH][KTL];
    __shared__ unsigned short sVlo[DH][KTL];
    __shared__ unsigned short sPhi[4][WQ][KTL];
    __shared__ unsigned short sPlo[4][WQ][KTL];

    const int t = threadIdx.x;
    const int l = t & 63;
    const int w = t >> 6;
    const int lg = l >> 4;
    const int lr = l & 15;

    const int hh_ = blockIdx.y, b = blockIdx.z;
    const int qb = blockIdx.x * BQ + w * WQ;

    const size_t hoff = (size_t)(b * NH + hh_) * SL * DH;
    const float* Kh = K + hoff;
    const float* Vh = V + hoff;
    const int*   Mw = M + ((size_t)b * SL + qb) * SL;
    float*       Pw = P + ((size_t)(b * NH + hh_) * SL + qb) * SL;
    float*       Ow = O + hoff + (size_t)qb * DH;

    short8 qhi[2], qlo[2];
    {
        const float* src0 = Q + hoff + (size_t)(qb + lr) * DH + lg * 8;
        #pragma unroll
        for (int ds = 0; ds < 2; ++ds) {
            const float* src = src0 + ds * 32;
            float4 a = *(const float4*)src;
            float4 bb = *(const float4*)(src + 4);
            float vals[8] = {a.x, a.y, a.z, a.w, bb.x, bb.y, bb.z, bb.w};
            #pragma unroll
            for (int j = 0; j < 8; ++j) {
                unsigned short hv, lv;
                bf_split(vals[j] * 0.125f, hv, lv);
                qhi[ds][j] = (short)hv;
                qlo[ds][j] = (short)lv;
            }
        }
    }

    auto stageK = [&](int k0) {
        #pragma unroll
        for (int u = 0; u < 2; ++u) {
            int idx = u * NT + t;
            int kr = idx >> 3;
            int dc = (idx & 7) * 8;
            const float* src = Kh + (size_t)(k0 + kr) * DH + dc;
            float4 a = *(const float4*)src;
            float4 bb = *(const float4*)(src + 4);
            float vals[8] = {a.x, a.y, a.z, a.w, bb.x, bb.y, bb.z, bb.w};
            unsigned int ph[4], pl[4];
            #pragma unroll
            for (int j = 0; j < 4; ++j) {
                unsigned short h0, l0, h1, l1;
                bf_split(vals[2 * j], h0, l0);
                bf_split(vals[2 * j + 1], h1, l1);
                ph[j] = (unsigned int)h0 | ((unsigned int)h1 << 16);
                pl[j] = (unsigned int)l0 | ((unsigned int)l1 << 16);
            }
            int dsw = dc ^ ((kr & 7) << 3);
            *(uint4*)&sKhi[kr][dsw] = make_uint4(ph[0], ph[1], ph[2], ph[3]);
            *(uint4*)&sKlo[kr][dsw] = make_uint4(pl[0], pl[1], pl[2], pl[3]);
        }
    };

    float m = -INFINITY, sum = 0.f;
    for (int kt = 0; kt < NKT; ++kt) {
        const int k0 = kt * KTL;
        __syncthreads();
        stageK(k0);
        __syncthreads();
        f32x4 acc[4];
        #pragma unroll
        for (int st = 0; st < 4; ++st) {
            const int krow = st * 16 + lr;
            const int sw = (krow & 7) << 3;
            f32x4 c = {0.f, 0.f, 0.f, 0.f};
            #pragma unroll
            for (int ds = 0; ds < 2; ++ds) {
                int dc = (ds * 32 + lg * 8) ^ sw;
                short8 ah = *(const short8*)&sKhi[krow][dc];
                short8 al = *(const short8*)&sKlo[krow][dc];
                c = MFMA(ah, qhi[ds], c);
                c = MFMA(ah, qlo[ds], c);
                c = MFMA(al, qhi[ds], c);
            }
            acc[st] = c;
        }
        float s[16];
        #pragma unroll
        for (int st = 0; st < 4; ++st) {
            const int4 mv = *(const int4*)(Mw + (size_t)lr * SL + k0 + st * 16 + lg * 4);
            s[st * 4 + 0] = mv.x ? acc[st][0] : -1e9f;
            s[st * 4 + 1] = mv.y ? acc[st][1] : -1e9f;
            s[st * 4 + 2] = mv.z ? acc[st][2] : -1e9f;
            s[st * 4 + 3] = mv.w ? acc[st][3] : -1e9f;
        }
        float tmax = s[0];
        #pragma unroll
        for (int j = 1; j < 16; ++j) tmax = fmaxf(tmax, s[j]);
        tmax = fmaxf(tmax, __shfl_xor(tmax, 16));
        tmax = fmaxf(tmax, __shfl_xor(tmax, 32));
        const float mn = fmaxf(m, tmax);
        float ts = 0.f;
        #pragma unroll
        for (int j = 0; j < 16; ++j) ts += __expf(s[j] - mn);
        ts += __shfl_xor(ts, 16);
        ts += __shfl_xor(ts, 32);
        sum = sum * __expf(m - mn) + ts;
        m = mn;
    }
    const float inv = 1.f / sum;

    f32x4 oacc[4];
    #pragma unroll
    for (int mt = 0; mt < 4; ++mt) oacc[mt] = (f32x4){0.f, 0.f, 0.f, 0.f};

    for (int kt = 0; kt < NKT; ++kt) {
        const int k0 = kt * KTL;
        __syncthreads();
        stageK(k0);
        {
            int d0 = (t & 15) * 4;
            int kl0 = (t >> 4) * 4;
            float4 r[4];
            #pragma unroll
            for (int i = 0; i < 4; ++i)
                r[i] = *(const float4*)(Vh + (size_t)(k0 + kl0 + i) * DH + d0);
            const float* rp = (const float*)r;
            #pragma unroll
            for (int j = 0; j < 4; ++j) {
                unsigned short hv[4], lv[4];
                #pragma unroll
                for (int i = 0; i < 4; ++i) bf_split(rp[i * 4 + j], hv[i], lv[i]);
                int d = d0 + j;
                int csw = kl0 ^ ((d & 7) << 3);
                uint2 uh, ul;
                uh.x = (unsigned int)hv[0] | ((unsigned int)hv[1] << 16);
                uh.y = (unsigned int)hv[2] | ((unsigned int)hv[3] << 16);
                ul.x = (unsigned int)lv[0] | ((unsigned int)lv[1] << 16);
                ul.y = (unsigned int)lv[2] | ((unsigned int)lv[3] << 16);
                *(uint2*)&sVhi[d][csw] = uh;
                *(uint2*)&sVlo[d][csw] = ul;
            }
        }
        __syncthreads();

        #pragma unroll
        for (int st = 0; st < 4; ++st) {
            const int krow = st * 16 + lr;
            const int sw = (krow & 7) << 3;
            f32x4 c = {0.f, 0.f, 0.f, 0.f};
            #pragma unroll
            for (int ds = 0; ds < 2; ++ds) {
                int dc = (ds * 32 + lg * 8) ^ sw;
                short8 ah = *(const short8*)&sKhi[krow][dc];
                short8 al = *(const short8*)&sKlo[krow][dc];
                c = MFMA(ah, qhi[ds], c);
                c = MFMA(ah, qlo[ds], c);
                c = MFMA(al, qhi[ds], c);
            }
            const int4 mv = *(const int4*)(Mw + (size_t)lr * SL + k0 + st * 16 + lg * 4);
            float p0 = mv.x ? __expf(c[0] - m) * inv : 0.f;
            float p1 = mv.y ? __expf(c[1] - m) * inv : 0.f;
            float p2 = mv.z ? __expf(c[2] - m) * inv : 0.f;
            float p3 = mv.w ? __expf(c[3] - m) * inv : 0.f;
            *(float4*)(Pw + (size_t)lr * SL + (k0 + st * 16 + lg * 4)) =
                make_float4(p0, p1, p2, p3);
            unsigned short hv[4], lv[4];
            bf_split(p0, hv[0], lv[0]);
            bf_split(p1, hv[1], lv[1]);
            bf_split(p2, hv[2], lv[2]);
            bf_split(p3, hv[3], lv[3]);
            int col = (st * 16 + lg * 4) ^ ((lr & 7) << 3);
            uint2 uh, ul;
            uh.x = (unsigned int)hv[0] | ((unsigned int)hv[1] << 16);
            uh.y = (unsigned int)hv[2] | ((unsigned int)hv[3] << 16);
            ul.x = (unsigned int)lv[0] | ((unsigned int)lv[1] << 16);
            ul.y = (unsigned int)lv[2] | ((unsigned int)lv[3] << 16);
            *(uint2*)&sPhi[w][lr][col] = uh;
            *(uint2*)&sPlo[w][lr][col] = ul;
        }

        short8 pbh[2], pbl[2];
        #pragma unroll
        for (int ks = 0; ks < 2; ++ks) {
            int col = (ks * 32 + lg * 8) ^ ((lr & 7) << 3);
            pbh[ks] = *(const short8*)&sPhi[w][lr][col];
            pbl[ks] = *(const short8*)&sPlo[w][lr][col];
        }
        #pragma unroll
        for (int mt = 0; mt < 4; ++mt) {
            const int d = mt * 16 + lr;
            const int swd = (d & 7) << 3;
            #pragma unroll
            for (int ks = 0; ks < 2; ++ks) {
                int col = (ks * 32 + lg * 8) ^ swd;
                short8 vh = *(const short8*)&sVhi[d][col];
                short8 vl = *(const short8*)&sVlo[d][col];
                oacc[mt] = MFMA(vh, pbh[ks], oacc[mt]);
                oacc[mt] = MFMA(vh, pbl[ks], oacc[mt]);
                oacc[mt] = MFMA(vl, pbh[ks], oacc[mt]);
            }
        }
    }

    #pragma unroll
    for (int mt = 0; mt < 4; ++mt) {
        float4 o = make_float4(oacc[mt][0], oacc[mt][1], oacc[mt][2], oacc[mt][3]);
        *(float4*)(Ow + (size_t)lr * DH + mt * 16 + lg * 4) = o;
    }
}

extern "C" void kernel_launch(void* const* d_in, const int* in_sizes, int n_in,
                              void* d_out, int out_size, void* d_ws, size_t ws_size,
                              hipStream_t stream) {
    const float* Q = (const float*)d_in[0];
    const float* K = (const float*)d_in[1];
    const float* V = (const float*)d_in[2];
    const int*   M = (const int*)d_in[3];
    float* O = (float*)d_out;
    float* P = O + (size_t)NB * NH * SL * DH;   // outputs: out, p_attn

    const size_t need = 4 * BLOB_SH * sizeof(unsigned short);   // 32 MB
    if (ws_size >= need) {
        unsigned short* khi = (unsigned short*)d_ws;
        unsigned short* klo = khi + BLOB_SH;
        unsigned short* vhi = klo + BLOB_SH;
        unsigned short* vlo = vhi + BLOB_SH;
        hipLaunchKernelGGL(prep_split, dim3(NKT, NH, NB), dim3(NT, 1, 1), 0, stream,
                           K, V, khi, klo, vhi, vlo);
        hipLaunchKernelGGL(attn_main, dim3(SL / BQ, NH, NB), dim3(NT, 1, 1), 0, stream,
                           Q, M, khi, klo, vhi, vlo, O, P);
    } else {
        hipLaunchKernelGGL(attn_fallback, dim3(SL / BQ, NH, NB), dim3(NT, 1, 1), 0, stream,
                           Q, K, V, M, O, P);
    }
}